// Round 1
// baseline (685.786 us; speedup 1.0000x reference)
//
#include <hip/hip_runtime.h>
#include <math.h>

typedef long long ll;

__device__ __forceinline__ int load_idx(const void* p, int i, int is64) {
  return is64 ? (int)((const ll*)p)[i] : ((const int*)p)[i];
}

// ---------- detect whether integer inputs are int64 or int32 ----------
__global__ void detect_kernel(const void* __restrict__ eidx, int ne,
                              const void* __restrict__ batch, int nb,
                              int* __restrict__ flags) {
  if (threadIdx.x == 0 && blockIdx.x == 0) {
    int e64 = 1;
    for (int k = 1; k <= 16; ++k) {
      int i = (int)((ll)k * (ne / 2 - 1) / 16);
      ll v = ((const ll*)eidx)[i];
      if (v < 0 || v >= (1LL << 31)) { e64 = 0; break; }
    }
    int b64 = 1;
    for (int k = 1; k <= 16; ++k) {
      int i = (int)((ll)k * (nb / 2 - 1) / 16);
      ll v = ((const ll*)batch)[i];
      if (v < 0 || v >= (1LL << 31)) { b64 = 0; break; }
    }
    flags[0] = e64; flags[1] = b64;
  }
}

// ---------- zero init (re-run every call: harness poisons ws once) ----------
__global__ void zero_kernel(int* __restrict__ deg, float* __restrict__ pool, int n) {
  int i = blockIdx.x * blockDim.x + threadIdx.x;
  if (i < n) deg[i] = 0;
  if (i < 192) pool[i] = 0.f;
}

// ---------- K1: h = x @ W1 (fused a_src1/a_dst1) ----------
// block 256 = 8 waves worth? (4 waves); thread t: q=t&31 -> j0=4q, p=t>>5 -> node pair
__global__ __launch_bounds__(256) void gemm1_kernel(
    const float* __restrict__ x, const float* __restrict__ W1,
    const float* __restrict__ att_src, const float* __restrict__ att_dst,
    float* __restrict__ h, float* __restrict__ a_src, float* __restrict__ a_dst,
    int nn) {
  __shared__ float4 Ws[128][32];   // 64 KB, W1[k][j] as float4 along j
  __shared__ float xs[16][128];    // 8 KB
  int t = threadIdx.x;
  const float4* W4 = (const float4*)W1;
  #pragma unroll
  for (int i = 0; i < 16; ++i) {
    int f = t + i * 256;           // 4096 float4s
    Ws[f >> 5][f & 31] = W4[f];
  }
  int q = t & 31, p = t >> 5;
  int n0 = blockIdx.x * 64;
  const float4 as4 = ((const float4*)att_src)[q];  // att flat [128] == j layout
  const float4 ad4 = ((const float4*)att_dst)[q];
  for (int g = 0; g < 64; g += 16) {
    __syncthreads();
    #pragma unroll
    for (int i = 0; i < 2; ++i) {
      int f = t + i * 256;         // 512 float4s = 16 rows
      int node = f >> 5, c4 = f & 31;
      int gn = n0 + g + node;
      float4 v = make_float4(0.f, 0.f, 0.f, 0.f);
      if (gn < nn) v = ((const float4*)x)[(size_t)gn * 32 + c4];
      *(float4*)&xs[node][c4 << 2] = v;
    }
    __syncthreads();
    float4 accA = make_float4(0,0,0,0), accB = make_float4(0,0,0,0);
    #pragma unroll 4
    for (int k = 0; k < 128; ++k) {
      float4 w = Ws[k][q];
      float xa = xs[p][k], xb = xs[p + 8][k];
      accA.x = fmaf(xa, w.x, accA.x);
      accA.y = fmaf(xa, w.y, accA.y);
      accA.z = fmaf(xa, w.z, accA.z);
      accA.w = fmaf(xa, w.w, accA.w);
      accB.x = fmaf(xb, w.x, accB.x);
      accB.y = fmaf(xb, w.y, accB.y);
      accB.z = fmaf(xb, w.z, accB.z);
      accB.w = fmaf(xb, w.w, accB.w);
    }
    int head = q >> 2;
    int nA = n0 + g + p, nB = n0 + g + 8 + p;
    float sA = accA.x*as4.x + accA.y*as4.y + accA.z*as4.z + accA.w*as4.w;
    float dA = accA.x*ad4.x + accA.y*ad4.y + accA.z*ad4.z + accA.w*ad4.w;
    float sB = accB.x*as4.x + accB.y*as4.y + accB.z*as4.z + accB.w*as4.w;
    float dB = accB.x*ad4.x + accB.y*ad4.y + accB.z*ad4.z + accB.w*ad4.w;
    sA += __shfl_xor(sA, 1); sA += __shfl_xor(sA, 2);
    dA += __shfl_xor(dA, 1); dA += __shfl_xor(dA, 2);
    sB += __shfl_xor(sB, 1); sB += __shfl_xor(sB, 2);
    dB += __shfl_xor(dB, 1); dB += __shfl_xor(dB, 2);
    if (nA < nn) {
      ((float4*)(h + (size_t)nA * 128))[q] = accA;
      if ((q & 3) == 0) { a_src[nA * 8 + head] = sA; a_dst[nA * 8 + head] = dA; }
    }
    if (nB < nn) {
      ((float4*)(h + (size_t)nB * 128))[q] = accB;
      if ((q & 3) == 0) { a_src[nB * 8 + head] = sB; a_dst[nB * 8 + head] = dB; }
    }
  }
}

// ---------- in-degree histogram (incl. self-loops) ----------
__global__ void hist_kernel(const void* __restrict__ eidx, int E, int EP,
                            const int* __restrict__ flags, int* __restrict__ deg) {
  int i = blockIdx.x * blockDim.x + threadIdx.x;
  if (i >= EP) return;
  int is64 = flags[0];
  int d = (i < E) ? load_idx(eidx, E + i, is64) : (i - E);
  atomicAdd(&deg[d], 1);
}

// ---------- single-block exclusive scan ----------
__global__ __launch_bounds__(1024) void scan_kernel(
    const int* __restrict__ deg, int* __restrict__ offs,
    int* __restrict__ cursor, int n) {
  __shared__ int sh[1024];
  __shared__ int carry_s;
  int t = threadIdx.x;
  if (t == 0) carry_s = 0;
  __syncthreads();
  int nchunks = (n + 1023) >> 10;
  for (int c = 0; c < nchunks; ++c) {
    int idx = (c << 10) + t;
    int v = (idx < n) ? deg[idx] : 0;
    sh[t] = v;
    __syncthreads();
    for (int off = 1; off < 1024; off <<= 1) {
      int add = (t >= off) ? sh[t - off] : 0;
      __syncthreads();
      sh[t] += add;
      __syncthreads();
    }
    int inc = sh[t];
    int carry = carry_s;
    if (idx < n) { int ex = carry + inc - v; offs[idx] = ex; cursor[idx] = ex; }
    __syncthreads();
    if (t == 1023) carry_s = carry + inc;
    __syncthreads();
  }
}

// ---------- scatter edges into dst-sorted order ----------
__global__ void scatter_kernel(const void* __restrict__ eidx, int E, int EP,
                               const int* __restrict__ flags,
                               int* __restrict__ cursor, int* __restrict__ ssrc) {
  int i = blockIdx.x * blockDim.x + threadIdx.x;
  if (i >= EP) return;
  int is64 = flags[0];
  int s, d;
  if (i < E) { s = load_idx(eidx, i, is64); d = load_idx(eidx, E + i, is64); }
  else { s = d = i - E; }
  int pos = atomicAdd(&cursor[d], 1);
  ssrc[pos] = s;
}

// ---------- layer-1 aggregation + ELU + layer-2 projection (fused) ----------
// one wave per node; lane owns 2 feature dims; after scatter, cursor[n]==end
__global__ __launch_bounds__(256) void node1_kernel(
    const int* __restrict__ ssrc, const int* __restrict__ offs, const int* __restrict__ ends,
    const float* __restrict__ h, const float* __restrict__ a_src, const float* __restrict__ a_dst,
    const float* __restrict__ b1, const float* __restrict__ W2,
    const float* __restrict__ att_s2, const float* __restrict__ att_d2,
    float* __restrict__ h2, float* __restrict__ as2, float* __restrict__ ad2, int nn) {
  int wid = threadIdx.x >> 6, lane = threadIdx.x & 63;
  int n = blockIdx.x * 4 + wid;
  if (n >= nn) return;
  int j = lane << 1;
  int hh = lane >> 3;
  float adst = a_dst[n * 8 + hh];
  int beg = offs[n], end = ends[n];
  float acc0 = 0.f, acc1 = 0.f, dsum = 0.f;
  for (int idx = beg; idx < end; ++idx) {
    int s = ssrc[idx];
    float e = a_src[s * 8 + hh] + adst;
    e = (e < 0.f) ? 0.2f * e : e;
    float ee = __expf(e);      // no max subtraction: mathematically identical
    float2 hv = *(const float2*)(h + (size_t)s * 128 + j);
    acc0 = fmaf(ee, hv.x, acc0);
    acc1 = fmaf(ee, hv.y, acc1);
    dsum += ee;
  }
  float inv = 1.f / dsum;
  float o0 = acc0 * inv + b1[j];
  float o1 = acc1 * inv + b1[j + 1];
  o0 = (o0 > 0.f) ? o0 : expm1f(o0);   // ELU
  o1 = (o1 > 0.f) ? o1 : expm1f(o1);
  // layer-2 projection: h2[c] = sum_j elu(out1)[j] * W2[j][c]
  float p0 = o0 * W2[j * 2]     + o1 * W2[(j + 1) * 2];
  float p1 = o0 * W2[j * 2 + 1] + o1 * W2[(j + 1) * 2 + 1];
  #pragma unroll
  for (int m = 1; m < 64; m <<= 1) { p0 += __shfl_xor(p0, m); p1 += __shfl_xor(p1, m); }
  if (lane == 0) {
    h2[n * 2] = p0; h2[n * 2 + 1] = p1;
    as2[n] = p0 * att_s2[0] + p1 * att_s2[1];
    ad2[n] = p0 * att_d2[0] + p1 * att_d2[1];
  }
}

// ---------- layer-2 aggregation + graph mean-pool accumulation ----------
__global__ __launch_bounds__(256) void node2_kernel(
    const int* __restrict__ ssrc, const int* __restrict__ offs, const int* __restrict__ ends,
    const float* __restrict__ h2, const float* __restrict__ as2, const float* __restrict__ ad2,
    const float* __restrict__ b2, const void* __restrict__ batch, const int* __restrict__ flags,
    float* __restrict__ pool, int nn) {
  __shared__ float psum[128];
  __shared__ float pcnt[64];
  int t = threadIdx.x;
  if (t < 128) psum[t] = 0.f;
  if (t < 64) pcnt[t] = 0.f;
  __syncthreads();
  int wid = t >> 6, lane = t & 63;
  int b64 = flags[1];
  for (int i = 0; i < 16; ++i) {
    int n = blockIdx.x * 64 + wid * 16 + i;
    if (n >= nn) break;
    float adst = ad2[n];
    int beg = offs[n], end = ends[n];
    float acc0 = 0.f, acc1 = 0.f, dsum = 0.f;
    for (int idx = beg + lane; idx < end; idx += 64) {
      int s = ssrc[idx];
      float e = as2[s] + adst;
      e = (e < 0.f) ? 0.2f * e : e;
      float ee = __expf(e);
      float2 hv = *(const float2*)(h2 + (size_t)s * 2);
      acc0 = fmaf(ee, hv.x, acc0);
      acc1 = fmaf(ee, hv.y, acc1);
      dsum += ee;
    }
    #pragma unroll
    for (int m = 1; m < 64; m <<= 1) {
      acc0 += __shfl_xor(acc0, m);
      acc1 += __shfl_xor(acc1, m);
      dsum += __shfl_xor(dsum, m);
    }
    if (lane == 0) {
      float o0 = acc0 / dsum + b2[0];
      float o1 = acc1 / dsum + b2[1];
      int g = load_idx(batch, n, b64);
      atomicAdd(&psum[g * 2], o0);
      atomicAdd(&psum[g * 2 + 1], o1);
      atomicAdd(&pcnt[g], 1.f);
    }
  }
  __syncthreads();
  if (t < 64 && pcnt[t] > 0.f) {
    atomicAdd(&pool[t * 2], psum[t * 2]);
    atomicAdd(&pool[t * 2 + 1], psum[t * 2 + 1]);
    atomicAdd(&pool[128 + t], pcnt[t]);
  }
}

// ---------- mean + log_softmax ----------
__global__ void finalize_kernel(const float* __restrict__ pool, float* __restrict__ out) {
  int g = threadIdx.x;
  if (g < 64) {
    float c = fmaxf(pool[128 + g], 1.f);
    float p0 = pool[g * 2] / c, p1 = pool[g * 2 + 1] / c;
    float m = fmaxf(p0, p1);
    float lse = m + logf(expf(p0 - m) + expf(p1 - m));
    out[g * 2] = p0 - lse;
    out[g * 2 + 1] = p1 - lse;
  }
}

extern "C" void kernel_launch(void* const* d_in, const int* in_sizes, int n_in,
                              void* d_out, int out_size, void* d_ws, size_t ws_size,
                              hipStream_t stream) {
  const float* x        = (const float*)d_in[0];
  const void* eidx      = d_in[1];
  const void* batch     = d_in[2];
  const float* W1       = (const float*)d_in[3];
  const float* att_src1 = (const float*)d_in[4];
  const float* att_dst1 = (const float*)d_in[5];
  const float* b1       = (const float*)d_in[6];
  const float* W2       = (const float*)d_in[7];
  const float* att_src2 = (const float*)d_in[8];
  const float* att_dst2 = (const float*)d_in[9];
  const float* b2       = (const float*)d_in[10];
  float* out = (float*)d_out;

  int N = in_sizes[0] / 128;
  int E = in_sizes[1] / 2;
  int EP = E + N;

  char* ws = (char*)d_ws;
  size_t o = 0;
  auto alloc = [&](size_t bytes) -> void* {
    void* p = ws + o;
    o += (bytes + 255) & ~(size_t)255;
    return p;
  };
  float* h      = (float*)alloc((size_t)N * 128 * 4);  // 51.2 MB
  float* a_src1 = (float*)alloc((size_t)N * 8 * 4);
  float* a_dst1 = (float*)alloc((size_t)N * 8 * 4);
  int*   deg    = (int*)alloc((size_t)N * 4);
  int*   offs   = (int*)alloc((size_t)N * 4);
  int*   cursor = (int*)alloc((size_t)N * 4);          // becomes 'end' after scatter
  int*   ssrc   = (int*)alloc((size_t)EP * 4);
  float* h2     = (float*)alloc((size_t)N * 2 * 4);
  float* as2    = (float*)alloc((size_t)N * 4);
  float* ad2    = (float*)alloc((size_t)N * 4);
  float* pool   = (float*)alloc(192 * 4);              // [128] sums + [64] counts
  int*   flags  = (int*)alloc(2 * 4);

  detect_kernel<<<1, 64, 0, stream>>>(eidx, 2 * E, batch, N, flags);
  zero_kernel<<<(N + 255) / 256, 256, 0, stream>>>(deg, pool, N);
  gemm1_kernel<<<(N + 63) / 64, 256, 0, stream>>>(x, W1, att_src1, att_dst1,
                                                  h, a_src1, a_dst1, N);
  hist_kernel<<<(EP + 255) / 256, 256, 0, stream>>>(eidx, E, EP, flags, deg);
  scan_kernel<<<1, 1024, 0, stream>>>(deg, offs, cursor, N);
  scatter_kernel<<<(EP + 255) / 256, 256, 0, stream>>>(eidx, E, EP, flags, cursor, ssrc);
  node1_kernel<<<(N + 3) / 4, 256, 0, stream>>>(ssrc, offs, cursor, h, a_src1, a_dst1,
                                                b1, W2, att_src2, att_dst2,
                                                h2, as2, ad2, N);
  node2_kernel<<<(N + 63) / 64, 256, 0, stream>>>(ssrc, offs, cursor, h2, as2, ad2,
                                                  b2, batch, flags, pool, N);
  finalize_kernel<<<1, 64, 0, stream>>>(pool, out);
}

// Round 2
// 503.868 us; speedup vs baseline: 1.3610x; 1.3610x over previous
//
#include <hip/hip_runtime.h>
#include <math.h>

typedef long long ll;
typedef unsigned int u32;
typedef unsigned short u16;

__device__ __forceinline__ int load_idx(const void* p, int i, int is64) {
  return is64 ? (int)((const ll*)p)[i] : ((const int*)p)[i];
}

__device__ __forceinline__ u16 f2bf(float f) {
  u32 u = __float_as_uint(f);
  u += 0x7FFFu + ((u >> 16) & 1u);
  return (u16)(u >> 16);
}

// ---------- detect whether integer inputs are int64 or int32 ----------
__global__ void detect_kernel(const void* __restrict__ eidx, int ne,
                              const void* __restrict__ batch, int nb,
                              int* __restrict__ flags) {
  if (threadIdx.x == 0 && blockIdx.x == 0) {
    int e64 = 1;
    for (int k = 1; k <= 16; ++k) {
      int i = (int)((ll)k * (ne / 2 - 1) / 16);
      ll v = ((const ll*)eidx)[i];
      if (v < 0 || v >= (1LL << 31)) { e64 = 0; break; }
    }
    int b64 = 1;
    for (int k = 1; k <= 16; ++k) {
      int i = (int)((ll)k * (nb / 2 - 1) / 16);
      ll v = ((const ll*)batch)[i];
      if (v < 0 || v >= (1LL << 31)) { b64 = 0; break; }
    }
    flags[0] = e64; flags[1] = b64;
  }
}

// ---------- zero init (re-run every call: harness poisons ws once) ----------
__global__ void zero_kernel(int* __restrict__ deg, float* __restrict__ pool, int n) {
  int i = blockIdx.x * blockDim.x + threadIdx.x;
  if (i < n) deg[i] = 0;
  if (i < 192) pool[i] = 0.f;
}

// ---------- K1: h = x @ W1 (f32 acc, bf16 store; fused a_src1/a_dst1) ----------
// 64 nodes/block, 2 chunks of 32 rows; thread: q=t&31 (4 cols), p=t>>5 (4 rows)
__global__ __launch_bounds__(256) void gemm1_kernel(
    const float* __restrict__ x, const float* __restrict__ W1,
    const float* __restrict__ att_src, const float* __restrict__ att_dst,
    u16* __restrict__ h, float* __restrict__ a_src, float* __restrict__ a_dst,
    int nn) {
  __shared__ float4 Ws[128][32];   // 64 KB
  __shared__ float xs[32][128];    // 16 KB
  int t = threadIdx.x;
  const float4* W4 = (const float4*)W1;
  #pragma unroll
  for (int i = 0; i < 16; ++i) {
    int f = t + i * 256;           // 4096 float4s
    Ws[f >> 5][f & 31] = W4[f];
  }
  int q = t & 31, p = t >> 5;
  int n0 = blockIdx.x * 64;
  const float4 as4 = ((const float4*)att_src)[q];
  const float4 ad4 = ((const float4*)att_dst)[q];
  for (int g = 0; g < 64; g += 32) {
    __syncthreads();
    #pragma unroll
    for (int i = 0; i < 4; ++i) {
      int f = t + i * 256;         // 1024 float4s = 32 rows
      int node = f >> 5, c4 = f & 31;
      int gn = n0 + g + node;
      float4 v = make_float4(0.f, 0.f, 0.f, 0.f);
      if (gn < nn) v = ((const float4*)x)[(size_t)gn * 32 + c4];
      *(float4*)&xs[node][c4 << 2] = v;
    }
    __syncthreads();
    float4 acc[4];
    #pragma unroll
    for (int r = 0; r < 4; ++r) acc[r] = make_float4(0.f, 0.f, 0.f, 0.f);
    #pragma unroll 4
    for (int k = 0; k < 128; ++k) {
      float4 w = Ws[k][q];
      #pragma unroll
      for (int r = 0; r < 4; ++r) {
        float xv = xs[p + r * 8][k];
        acc[r].x = fmaf(xv, w.x, acc[r].x);
        acc[r].y = fmaf(xv, w.y, acc[r].y);
        acc[r].z = fmaf(xv, w.z, acc[r].z);
        acc[r].w = fmaf(xv, w.w, acc[r].w);
      }
    }
    int head = q >> 2;
    #pragma unroll
    for (int r = 0; r < 4; ++r) {
      int n = n0 + g + p + r * 8;
      float s = acc[r].x*as4.x + acc[r].y*as4.y + acc[r].z*as4.z + acc[r].w*as4.w;
      float d = acc[r].x*ad4.x + acc[r].y*ad4.y + acc[r].z*ad4.z + acc[r].w*ad4.w;
      s += __shfl_xor(s, 1); s += __shfl_xor(s, 2);
      d += __shfl_xor(d, 1); d += __shfl_xor(d, 2);
      if (n < nn) {
        uint2 pk;
        pk.x = (u32)f2bf(acc[r].x) | ((u32)f2bf(acc[r].y) << 16);
        pk.y = (u32)f2bf(acc[r].z) | ((u32)f2bf(acc[r].w) << 16);
        ((uint2*)(h + (size_t)n * 128))[q] = pk;
        if ((q & 3) == 0) { a_src[n * 8 + head] = s; a_dst[n * 8 + head] = d; }
      }
    }
  }
}

// ---------- in-degree histogram (incl. self-loops) ----------
__global__ void hist_kernel(const void* __restrict__ eidx, int E, int EP,
                            const int* __restrict__ flags, int* __restrict__ deg) {
  int i = blockIdx.x * blockDim.x + threadIdx.x;
  if (i >= EP) return;
  int is64 = flags[0];
  int d = (i < E) ? load_idx(eidx, E + i, is64) : (i - E);
  atomicAdd(&deg[d], 1);
}

// ---------- two-level scan ----------
__global__ __launch_bounds__(256) void scan_blk(const int* __restrict__ deg,
                                                int* __restrict__ offs,
                                                int* __restrict__ bsums, int n) {
  int t = threadIdx.x;
  int i = blockIdx.x * 256 + t;
  int v = (i < n) ? deg[i] : 0;
  int lane = t & 63, w = t >> 6;
  int s = v;
  #pragma unroll
  for (int off = 1; off < 64; off <<= 1) {
    int u = __shfl_up(s, off);
    if (lane >= off) s += u;
  }
  __shared__ int wsum[4];
  if (lane == 63) wsum[w] = s;
  __syncthreads();
  int add = 0;
  for (int k = 0; k < w; ++k) add += wsum[k];
  int incl = s + add;
  if (i < n) offs[i] = incl - v;          // block-local exclusive
  if (t == 255) bsums[blockIdx.x] = incl; // block total
}

__global__ __launch_bounds__(1024) void scan_top(int* __restrict__ bsums, int nb) {
  int t = threadIdx.x;
  int v = (t < nb) ? bsums[t] : 0;
  int lane = t & 63, w = t >> 6;
  int s = v;
  #pragma unroll
  for (int off = 1; off < 64; off <<= 1) {
    int u = __shfl_up(s, off);
    if (lane >= off) s += u;
  }
  __shared__ int ws[16];
  if (lane == 63) ws[w] = s;
  __syncthreads();
  int add = 0;
  for (int k = 0; k < w; ++k) add += ws[k];
  if (t < nb) bsums[t] = s + add - v;     // exclusive
}

__global__ void scan_add(int* __restrict__ offs, const int* __restrict__ bsums,
                         int* __restrict__ cursor, int n) {
  int i = blockIdx.x * 256 + threadIdx.x;
  if (i < n) {
    int v = offs[i] + bsums[blockIdx.x];
    offs[i] = v;
    cursor[i] = v;
  }
}

// ---------- scatter edges into dst-sorted order ----------
__global__ void scatter_kernel(const void* __restrict__ eidx, int E, int EP,
                               const int* __restrict__ flags,
                               int* __restrict__ cursor, int* __restrict__ ssrc) {
  int i = blockIdx.x * blockDim.x + threadIdx.x;
  if (i >= EP) return;
  int is64 = flags[0];
  int s, d;
  if (i < E) { s = load_idx(eidx, i, is64); d = load_idx(eidx, E + i, is64); }
  else { s = d = i - E; }
  int pos = atomicAdd(&cursor[d], 1);
  ssrc[pos] = s;
}

// ---------- layer-1 aggregation + ELU + layer-2 projection (fused, bf16 h) ----------
__global__ __launch_bounds__(256) void node1_kernel(
    const int* __restrict__ ssrc, const int* __restrict__ offs, const int* __restrict__ ends,
    const u16* __restrict__ h, const float* __restrict__ a_src, const float* __restrict__ a_dst,
    const float* __restrict__ b1, const float* __restrict__ W2,
    const float* __restrict__ att_s2, const float* __restrict__ att_d2,
    float* __restrict__ h2, float* __restrict__ as2, float* __restrict__ ad2, int nn) {
  int wid = threadIdx.x >> 6, lane = threadIdx.x & 63;
  int n = blockIdx.x * 4 + wid;
  if (n >= nn) return;
  int j = lane << 1;
  int hh = lane >> 3;
  float adst = a_dst[n * 8 + hh];
  int beg = offs[n], end = ends[n];
  float acc0 = 0.f, acc1 = 0.f, dsum = 0.f;
  for (int idx = beg; idx < end; ++idx) {
    int s = ssrc[idx];
    float e = a_src[s * 8 + hh] + adst;
    e = (e < 0.f) ? 0.2f * e : e;
    float ee = __expf(e);      // no max subtraction: mathematically identical
    u32 v = ((const u32*)(h + (size_t)s * 128))[lane];
    float h0 = __uint_as_float(v << 16);
    float h1 = __uint_as_float(v & 0xFFFF0000u);
    acc0 = fmaf(ee, h0, acc0);
    acc1 = fmaf(ee, h1, acc1);
    dsum += ee;
  }
  float inv = 1.f / dsum;
  float o0 = acc0 * inv + b1[j];
  float o1 = acc1 * inv + b1[j + 1];
  o0 = (o0 > 0.f) ? o0 : expm1f(o0);   // ELU
  o1 = (o1 > 0.f) ? o1 : expm1f(o1);
  float p0 = o0 * W2[j * 2]     + o1 * W2[(j + 1) * 2];
  float p1 = o0 * W2[j * 2 + 1] + o1 * W2[(j + 1) * 2 + 1];
  #pragma unroll
  for (int m = 1; m < 64; m <<= 1) { p0 += __shfl_xor(p0, m); p1 += __shfl_xor(p1, m); }
  if (lane == 0) {
    h2[n * 2] = p0; h2[n * 2 + 1] = p1;
    as2[n] = p0 * att_s2[0] + p1 * att_s2[1];
    ad2[n] = p0 * att_d2[0] + p1 * att_d2[1];
  }
}

// ---------- layer-2 aggregation + graph mean-pool accumulation ----------
__global__ __launch_bounds__(256) void node2_kernel(
    const int* __restrict__ ssrc, const int* __restrict__ offs, const int* __restrict__ ends,
    const float* __restrict__ h2, const float* __restrict__ as2, const float* __restrict__ ad2,
    const float* __restrict__ b2, const void* __restrict__ batch, const int* __restrict__ flags,
    float* __restrict__ pool, int nn) {
  __shared__ float psum[128];
  __shared__ float pcnt[64];
  int t = threadIdx.x;
  if (t < 128) psum[t] = 0.f;
  if (t < 64) pcnt[t] = 0.f;
  __syncthreads();
  int wid = t >> 6, lane = t & 63;
  int b64 = flags[1];
  for (int i = 0; i < 16; ++i) {
    int n = blockIdx.x * 64 + wid * 16 + i;
    if (n >= nn) break;
    float adst = ad2[n];
    int beg = offs[n], end = ends[n];
    float acc0 = 0.f, acc1 = 0.f, dsum = 0.f;
    for (int idx = beg + lane; idx < end; idx += 64) {
      int s = ssrc[idx];
      float e = as2[s] + adst;
      e = (e < 0.f) ? 0.2f * e : e;
      float ee = __expf(e);
      float2 hv = *(const float2*)(h2 + (size_t)s * 2);
      acc0 = fmaf(ee, hv.x, acc0);
      acc1 = fmaf(ee, hv.y, acc1);
      dsum += ee;
    }
    #pragma unroll
    for (int m = 1; m < 64; m <<= 1) {
      acc0 += __shfl_xor(acc0, m);
      acc1 += __shfl_xor(acc1, m);
      dsum += __shfl_xor(dsum, m);
    }
    if (lane == 0) {
      float o0 = acc0 / dsum + b2[0];
      float o1 = acc1 / dsum + b2[1];
      int g = load_idx(batch, n, b64);
      atomicAdd(&psum[g * 2], o0);
      atomicAdd(&psum[g * 2 + 1], o1);
      atomicAdd(&pcnt[g], 1.f);
    }
  }
  __syncthreads();
  if (t < 64 && pcnt[t] > 0.f) {
    atomicAdd(&pool[t * 2], psum[t * 2]);
    atomicAdd(&pool[t * 2 + 1], psum[t * 2 + 1]);
    atomicAdd(&pool[128 + t], pcnt[t]);
  }
}

// ---------- mean + log_softmax ----------
__global__ void finalize_kernel(const float* __restrict__ pool, float* __restrict__ out) {
  int g = threadIdx.x;
  if (g < 64) {
    float c = fmaxf(pool[128 + g], 1.f);
    float p0 = pool[g * 2] / c, p1 = pool[g * 2 + 1] / c;
    float m = fmaxf(p0, p1);
    float lse = m + logf(expf(p0 - m) + expf(p1 - m));
    out[g * 2] = p0 - lse;
    out[g * 2 + 1] = p1 - lse;
  }
}

extern "C" void kernel_launch(void* const* d_in, const int* in_sizes, int n_in,
                              void* d_out, int out_size, void* d_ws, size_t ws_size,
                              hipStream_t stream) {
  const float* x        = (const float*)d_in[0];
  const void* eidx      = d_in[1];
  const void* batch     = d_in[2];
  const float* W1       = (const float*)d_in[3];
  const float* att_src1 = (const float*)d_in[4];
  const float* att_dst1 = (const float*)d_in[5];
  const float* b1       = (const float*)d_in[6];
  const float* W2       = (const float*)d_in[7];
  const float* att_src2 = (const float*)d_in[8];
  const float* att_dst2 = (const float*)d_in[9];
  const float* b2       = (const float*)d_in[10];
  float* out = (float*)d_out;

  int N = in_sizes[0] / 128;
  int E = in_sizes[1] / 2;
  int EP = E + N;
  int NB = (N + 255) / 256;

  char* ws = (char*)d_ws;
  size_t o = 0;
  auto alloc = [&](size_t bytes) -> void* {
    void* p = ws + o;
    o += (bytes + 255) & ~(size_t)255;
    return p;
  };
  u16*   h      = (u16*)alloc((size_t)N * 128 * 2);    // 25.6 MB bf16
  float* a_src1 = (float*)alloc((size_t)N * 8 * 4);
  float* a_dst1 = (float*)alloc((size_t)N * 8 * 4);
  int*   deg    = (int*)alloc((size_t)N * 4);
  int*   offs   = (int*)alloc((size_t)N * 4);
  int*   cursor = (int*)alloc((size_t)N * 4);          // becomes 'end' after scatter
  int*   bsums  = (int*)alloc((size_t)(NB + 1) * 4);
  int*   ssrc   = (int*)alloc((size_t)EP * 4);
  float* h2     = (float*)alloc((size_t)N * 2 * 4);
  float* as2    = (float*)alloc((size_t)N * 4);
  float* ad2    = (float*)alloc((size_t)N * 4);
  float* pool   = (float*)alloc(192 * 4);              // [128] sums + [64] counts
  int*   flags  = (int*)alloc(2 * 4);

  detect_kernel<<<1, 64, 0, stream>>>(eidx, 2 * E, batch, N, flags);
  zero_kernel<<<(N + 255) / 256, 256, 0, stream>>>(deg, pool, N);
  gemm1_kernel<<<(N + 63) / 64, 256, 0, stream>>>(x, W1, att_src1, att_dst1,
                                                  h, a_src1, a_dst1, N);
  hist_kernel<<<(EP + 255) / 256, 256, 0, stream>>>(eidx, E, EP, flags, deg);
  scan_blk<<<NB, 256, 0, stream>>>(deg, offs, bsums, N);
  scan_top<<<1, 1024, 0, stream>>>(bsums, NB);
  scan_add<<<NB, 256, 0, stream>>>(offs, bsums, cursor, N);
  scatter_kernel<<<(EP + 255) / 256, 256, 0, stream>>>(eidx, E, EP, flags, cursor, ssrc);
  node1_kernel<<<(N + 3) / 4, 256, 0, stream>>>(ssrc, offs, cursor, h, a_src1, a_dst1,
                                                b1, W2, att_src2, att_dst2,
                                                h2, as2, ad2, N);
  node2_kernel<<<(N + 63) / 64, 256, 0, stream>>>(ssrc, offs, cursor, h2, as2, ad2,
                                                  b2, batch, flags, pool, N);
  finalize_kernel<<<1, 64, 0, stream>>>(pool, out);
}

// Round 3
// 412.524 us; speedup vs baseline: 1.6624x; 1.2214x over previous
//
#include <hip/hip_runtime.h>
#include <math.h>

typedef long long ll;
typedef unsigned int u32;
typedef unsigned short u16;

__device__ __forceinline__ int load_idx(const void* p, int i, int is64) {
  return is64 ? (int)((const ll*)p)[i] : ((const int*)p)[i];
}

__device__ __forceinline__ u16 f2bf(float f) {
  u32 u = __float_as_uint(f);
  u += 0x7FFFu + ((u >> 16) & 1u);
  return (u16)(u >> 16);
}

// ---------- detect whether integer inputs are int64 or int32 ----------
__global__ void detect_kernel(const void* __restrict__ eidx, int ne,
                              const void* __restrict__ batch, int nb,
                              int* __restrict__ flags) {
  if (threadIdx.x == 0 && blockIdx.x == 0) {
    int e64 = 1;
    for (int k = 1; k <= 16; ++k) {
      int i = (int)((ll)k * (ne / 2 - 1) / 16);
      ll v = ((const ll*)eidx)[i];
      if (v < 0 || v >= (1LL << 31)) { e64 = 0; break; }
    }
    int b64 = 1;
    for (int k = 1; k <= 16; ++k) {
      int i = (int)((ll)k * (nb / 2 - 1) / 16);
      ll v = ((const ll*)batch)[i];
      if (v < 0 || v >= (1LL << 31)) { b64 = 0; break; }
    }
    flags[0] = e64; flags[1] = b64;
  }
}

// ---------- zero init (re-run every call: harness poisons ws once) ----------
__global__ void zero_kernel(int* __restrict__ deg, float* __restrict__ pool, int n) {
  int i = blockIdx.x * blockDim.x + threadIdx.x;
  if (i < n) deg[i] = 0;
  if (i < 192) pool[i] = 0.f;
}

// ---------- K1: h = x @ W1 (f32 acc, bf16 store; fused a_src1/a_dst1) ----------
__global__ __launch_bounds__(256) void gemm1_kernel(
    const float* __restrict__ x, const float* __restrict__ W1,
    const float* __restrict__ att_src, const float* __restrict__ att_dst,
    u16* __restrict__ h, float* __restrict__ a_src, float* __restrict__ a_dst,
    int nn) {
  __shared__ float4 Ws[128][32];   // 64 KB
  __shared__ float xs[32][128];    // 16 KB
  int t = threadIdx.x;
  const float4* W4 = (const float4*)W1;
  #pragma unroll
  for (int i = 0; i < 16; ++i) {
    int f = t + i * 256;           // 4096 float4s
    Ws[f >> 5][f & 31] = W4[f];
  }
  int q = t & 31, p = t >> 5;
  int n0 = blockIdx.x * 64;
  const float4 as4 = ((const float4*)att_src)[q];
  const float4 ad4 = ((const float4*)att_dst)[q];
  for (int g = 0; g < 64; g += 32) {
    __syncthreads();
    #pragma unroll
    for (int i = 0; i < 4; ++i) {
      int f = t + i * 256;         // 1024 float4s = 32 rows
      int node = f >> 5, c4 = f & 31;
      int gn = n0 + g + node;
      float4 v = make_float4(0.f, 0.f, 0.f, 0.f);
      if (gn < nn) v = ((const float4*)x)[(size_t)gn * 32 + c4];
      *(float4*)&xs[node][c4 << 2] = v;
    }
    __syncthreads();
    float4 acc[4];
    #pragma unroll
    for (int r = 0; r < 4; ++r) acc[r] = make_float4(0.f, 0.f, 0.f, 0.f);
    #pragma unroll 4
    for (int k = 0; k < 128; ++k) {
      float4 w = Ws[k][q];
      #pragma unroll
      for (int r = 0; r < 4; ++r) {
        float xv = xs[p + r * 8][k];
        acc[r].x = fmaf(xv, w.x, acc[r].x);
        acc[r].y = fmaf(xv, w.y, acc[r].y);
        acc[r].z = fmaf(xv, w.z, acc[r].z);
        acc[r].w = fmaf(xv, w.w, acc[r].w);
      }
    }
    int head = q >> 2;
    #pragma unroll
    for (int r = 0; r < 4; ++r) {
      int n = n0 + g + p + r * 8;
      float s = acc[r].x*as4.x + acc[r].y*as4.y + acc[r].z*as4.z + acc[r].w*as4.w;
      float d = acc[r].x*ad4.x + acc[r].y*ad4.y + acc[r].z*ad4.z + acc[r].w*ad4.w;
      s += __shfl_xor(s, 1); s += __shfl_xor(s, 2);
      d += __shfl_xor(d, 1); d += __shfl_xor(d, 2);
      if (n < nn) {
        uint2 pk;
        pk.x = (u32)f2bf(acc[r].x) | ((u32)f2bf(acc[r].y) << 16);
        pk.y = (u32)f2bf(acc[r].z) | ((u32)f2bf(acc[r].w) << 16);
        ((uint2*)(h + (size_t)n * 128))[q] = pk;
        if ((q & 3) == 0) { a_src[n * 8 + head] = s; a_dst[n * 8 + head] = d; }
      }
    }
  }
}

// ---------- in-degree histogram (incl. self-loops) ----------
__global__ void hist_kernel(const void* __restrict__ eidx, int E, int EP,
                            const int* __restrict__ flags, int* __restrict__ deg) {
  int i = blockIdx.x * blockDim.x + threadIdx.x;
  if (i >= EP) return;
  int is64 = flags[0];
  int d = (i < E) ? load_idx(eidx, E + i, is64) : (i - E);
  atomicAdd(&deg[d], 1);
}

// ---------- two-level scan ----------
__global__ __launch_bounds__(256) void scan_blk(const int* __restrict__ deg,
                                                int* __restrict__ offs,
                                                int* __restrict__ bsums, int n) {
  int t = threadIdx.x;
  int i = blockIdx.x * 256 + t;
  int v = (i < n) ? deg[i] : 0;
  int lane = t & 63, w = t >> 6;
  int s = v;
  #pragma unroll
  for (int off = 1; off < 64; off <<= 1) {
    int u = __shfl_up(s, off);
    if (lane >= off) s += u;
  }
  __shared__ int wsum[4];
  if (lane == 63) wsum[w] = s;
  __syncthreads();
  int add = 0;
  for (int k = 0; k < w; ++k) add += wsum[k];
  int incl = s + add;
  if (i < n) offs[i] = incl - v;          // block-local exclusive
  if (t == 255) bsums[blockIdx.x] = incl; // block total
}

__global__ __launch_bounds__(1024) void scan_top(int* __restrict__ bsums, int nb) {
  int t = threadIdx.x;
  int v = (t < nb) ? bsums[t] : 0;
  int lane = t & 63, w = t >> 6;
  int s = v;
  #pragma unroll
  for (int off = 1; off < 64; off <<= 1) {
    int u = __shfl_up(s, off);
    if (lane >= off) s += u;
  }
  __shared__ int ws[16];
  if (lane == 63) ws[w] = s;
  __syncthreads();
  int add = 0;
  for (int k = 0; k < w; ++k) add += ws[k];
  if (t < nb) bsums[t] = s + add - v;     // exclusive
}

__global__ void scan_add(int* __restrict__ offs, const int* __restrict__ bsums,
                         int* __restrict__ cursor, int n) {
  int i = blockIdx.x * 256 + threadIdx.x;
  if (i < n) {
    int v = offs[i] + bsums[blockIdx.x];
    offs[i] = v;
    cursor[i] = v;
  }
}

// ---------- scatter edges into dst-sorted order ----------
__global__ void scatter_kernel(const void* __restrict__ eidx, int E, int EP,
                               const int* __restrict__ flags,
                               int* __restrict__ cursor, int* __restrict__ ssrc) {
  int i = blockIdx.x * blockDim.x + threadIdx.x;
  if (i >= EP) return;
  int is64 = flags[0];
  int s, d;
  if (i < E) { s = load_idx(eidx, i, is64); d = load_idx(eidx, E + i, is64); }
  else { s = d = i - E; }
  int pos = atomicAdd(&cursor[d], 1);
  ssrc[pos] = s;
}

// ---------- layer-1 aggregation + ELU + layer-2 projection ----------
// one wave per node; lane owns 2 features; 8-wide unrolled, predicated tail
__global__ __launch_bounds__(256) void node1_kernel(
    const int* __restrict__ ssrc, const int* __restrict__ offs, const int* __restrict__ ends,
    const u16* __restrict__ h, const float* __restrict__ a_src, const float* __restrict__ a_dst,
    const float* __restrict__ b1, const float* __restrict__ W2,
    const float* __restrict__ att_s2, const float* __restrict__ att_d2,
    float* __restrict__ h2, float* __restrict__ as2, float* __restrict__ ad2, int nn) {
  int wid = threadIdx.x >> 6, lane = threadIdx.x & 63;
  int n = blockIdx.x * 4 + wid;
  if (n >= nn) return;
  int j = lane << 1;
  int hh = lane >> 3;
  float adst = a_dst[n * 8 + hh];
  int beg = offs[n], end = ends[n];   // deg >= 1 (self-loop)
  float acc0 = 0.f, acc1 = 0.f, dsum = 0.f;
  for (int base = beg; base < end; base += 8) {
    int s[8]; u32 v[8]; float ea[8];
    #pragma unroll
    for (int u = 0; u < 8; ++u) {
      int id = base + u;
      s[u] = ssrc[id < end ? id : end - 1];
    }
    #pragma unroll
    for (int u = 0; u < 8; ++u) {
      v[u]  = ((const u32*)(h + (size_t)s[u] * 128))[lane];
      ea[u] = a_src[s[u] * 8 + hh];
    }
    #pragma unroll
    for (int u = 0; u < 8; ++u) {
      float e = ea[u] + adst;
      e = (e < 0.f) ? 0.2f * e : e;
      float ee = (base + u < end) ? __expf(e) : 0.f;
      float h0 = __uint_as_float(v[u] << 16);
      float h1 = __uint_as_float(v[u] & 0xFFFF0000u);
      acc0 = fmaf(ee, h0, acc0);
      acc1 = fmaf(ee, h1, acc1);
      dsum += ee;
    }
  }
  float inv = 1.f / dsum;
  float o0 = acc0 * inv + b1[j];
  float o1 = acc1 * inv + b1[j + 1];
  o0 = (o0 > 0.f) ? o0 : expm1f(o0);   // ELU
  o1 = (o1 > 0.f) ? o1 : expm1f(o1);
  float p0 = o0 * W2[j * 2]     + o1 * W2[(j + 1) * 2];
  float p1 = o0 * W2[j * 2 + 1] + o1 * W2[(j + 1) * 2 + 1];
  #pragma unroll
  for (int m = 1; m < 64; m <<= 1) { p0 += __shfl_xor(p0, m); p1 += __shfl_xor(p1, m); }
  if (lane == 0) {
    h2[n * 2] = p0; h2[n * 2 + 1] = p1;
    as2[n] = p0 * att_s2[0] + p1 * att_s2[1];
    ad2[n] = p0 * att_d2[0] + p1 * att_d2[1];
  }
}

// ---------- layer-2 aggregation + graph mean-pool (8-lane group per node) ----------
__global__ __launch_bounds__(256) void node2_kernel(
    const int* __restrict__ ssrc, const int* __restrict__ offs, const int* __restrict__ ends,
    const float* __restrict__ h2, const float* __restrict__ as2, const float* __restrict__ ad2,
    const float* __restrict__ b2, const void* __restrict__ batch, const int* __restrict__ flags,
    float* __restrict__ pool, int nn) {
  __shared__ float psum[128];
  __shared__ float pcnt[64];
  int t = threadIdx.x;
  if (t < 128) psum[t] = 0.f;
  if (t < 64) pcnt[t] = 0.f;
  __syncthreads();
  int grp = t >> 3, lane8 = t & 7;    // 32 groups of 8 lanes
  int b64 = flags[1];
  int n = blockIdx.x * 32 + grp;
  if (n < nn) {
    float adst = ad2[n];
    int beg = offs[n], end = ends[n];
    float acc0 = 0.f, acc1 = 0.f, dsum = 0.f;
    for (int idx = beg + lane8; idx < end; idx += 8) {
      int s = ssrc[idx];
      float e = as2[s] + adst;
      e = (e < 0.f) ? 0.2f * e : e;
      float ee = __expf(e);
      float2 hv = *(const float2*)(h2 + (size_t)s * 2);
      acc0 = fmaf(ee, hv.x, acc0);
      acc1 = fmaf(ee, hv.y, acc1);
      dsum += ee;
    }
    #pragma unroll
    for (int m = 1; m < 8; m <<= 1) {   // xor mask <8 stays within the 8-group
      acc0 += __shfl_xor(acc0, m);
      acc1 += __shfl_xor(acc1, m);
      dsum += __shfl_xor(dsum, m);
    }
    if (lane8 == 0) {
      float o0 = acc0 / dsum + b2[0];
      float o1 = acc1 / dsum + b2[1];
      int g = load_idx(batch, n, b64);
      atomicAdd(&psum[g * 2], o0);
      atomicAdd(&psum[g * 2 + 1], o1);
      atomicAdd(&pcnt[g], 1.f);
    }
  }
  __syncthreads();
  if (t < 64 && pcnt[t] > 0.f) {
    atomicAdd(&pool[t * 2], psum[t * 2]);
    atomicAdd(&pool[t * 2 + 1], psum[t * 2 + 1]);
    atomicAdd(&pool[128 + t], pcnt[t]);
  }
}

// ---------- mean + log_softmax ----------
__global__ void finalize_kernel(const float* __restrict__ pool, float* __restrict__ out) {
  int g = threadIdx.x;
  if (g < 64) {
    float c = fmaxf(pool[128 + g], 1.f);
    float p0 = pool[g * 2] / c, p1 = pool[g * 2 + 1] / c;
    float m = fmaxf(p0, p1);
    float lse = m + logf(expf(p0 - m) + expf(p1 - m));
    out[g * 2] = p0 - lse;
    out[g * 2 + 1] = p1 - lse;
  }
}

extern "C" void kernel_launch(void* const* d_in, const int* in_sizes, int n_in,
                              void* d_out, int out_size, void* d_ws, size_t ws_size,
                              hipStream_t stream) {
  const float* x        = (const float*)d_in[0];
  const void* eidx      = d_in[1];
  const void* batch     = d_in[2];
  const float* W1       = (const float*)d_in[3];
  const float* att_src1 = (const float*)d_in[4];
  const float* att_dst1 = (const float*)d_in[5];
  const float* b1       = (const float*)d_in[6];
  const float* W2       = (const float*)d_in[7];
  const float* att_src2 = (const float*)d_in[8];
  const float* att_dst2 = (const float*)d_in[9];
  const float* b2       = (const float*)d_in[10];
  float* out = (float*)d_out;

  int N = in_sizes[0] / 128;
  int E = in_sizes[1] / 2;
  int EP = E + N;
  int NB = (N + 255) / 256;

  char* ws = (char*)d_ws;
  size_t o = 0;
  auto alloc = [&](size_t bytes) -> void* {
    void* p = ws + o;
    o += (bytes + 255) & ~(size_t)255;
    return p;
  };
  u16*   h      = (u16*)alloc((size_t)N * 128 * 2);    // 25.6 MB bf16
  float* a_src1 = (float*)alloc((size_t)N * 8 * 4);
  float* a_dst1 = (float*)alloc((size_t)N * 8 * 4);
  int*   deg    = (int*)alloc((size_t)N * 4);
  int*   offs   = (int*)alloc((size_t)N * 4);
  int*   cursor = (int*)alloc((size_t)N * 4);          // becomes 'end' after scatter
  int*   bsums  = (int*)alloc((size_t)(NB + 1) * 4);
  int*   ssrc   = (int*)alloc((size_t)EP * 4);
  float* h2     = (float*)alloc((size_t)N * 2 * 4);
  float* as2    = (float*)alloc((size_t)N * 4);
  float* ad2    = (float*)alloc((size_t)N * 4);
  float* pool   = (float*)alloc(192 * 4);              // [128] sums + [64] counts
  int*   flags  = (int*)alloc(2 * 4);

  detect_kernel<<<1, 64, 0, stream>>>(eidx, 2 * E, batch, N, flags);
  zero_kernel<<<(N + 255) / 256, 256, 0, stream>>>(deg, pool, N);
  gemm1_kernel<<<(N + 63) / 64, 256, 0, stream>>>(x, W1, att_src1, att_dst1,
                                                  h, a_src1, a_dst1, N);
  hist_kernel<<<(EP + 255) / 256, 256, 0, stream>>>(eidx, E, EP, flags, deg);
  scan_blk<<<NB, 256, 0, stream>>>(deg, offs, bsums, N);
  scan_top<<<1, 1024, 0, stream>>>(bsums, NB);
  scan_add<<<NB, 256, 0, stream>>>(offs, bsums, cursor, N);
  scatter_kernel<<<(EP + 255) / 256, 256, 0, stream>>>(eidx, E, EP, flags, cursor, ssrc);
  node1_kernel<<<(N + 3) / 4, 256, 0, stream>>>(ssrc, offs, cursor, h, a_src1, a_dst1,
                                                b1, W2, att_src2, att_dst2,
                                                h2, as2, ad2, N);
  node2_kernel<<<(N + 31) / 32, 256, 0, stream>>>(ssrc, offs, cursor, h2, as2, ad2,
                                                  b2, batch, flags, pool, N);
  finalize_kernel<<<1, 64, 0, stream>>>(pool, out);
}